// Round 10
// baseline (585.132 us; speedup 1.0000x reference)
//
#include <hip/hip_runtime.h>
#include <math.h>

#define N_NODES 100000
#define N_EDGES 1600000
#define D 128
#define NCLASS 10
#define NLAYERS 3
#define BN_EPS 1e-5f

#define LDA 136        // padded LDS row stride in bf16 elems
#define BUCKET_SH 7    // 128 nodes per bucket
#define NBUK 782       // ceil(100000/128)
#define NBLK 256       // partition blocks (== scan chunk size -> psums[i] = bucket i base)
#define CHUNK 6250     // N_EDGES / NBLK (exact)
#define SCAN_BLKS NBUK

typedef __attribute__((ext_vector_type(8))) short bf16x8;
typedef __attribute__((ext_vector_type(4))) float f32x4;
typedef __attribute__((ext_vector_type(4))) uint u32x4;

__device__ __forceinline__ ushort f2b(float x) {          // RNE fp32 -> bf16
    uint u = __float_as_uint(x);
    return (ushort)((u + 0x7fffu + ((u >> 16) & 1u)) >> 16);
}
__device__ __forceinline__ float b2f(uint u) {            // bf16 bits -> fp32 (exact)
    return __uint_as_float(u << 16);
}
__device__ __forceinline__ uint pack2(float a, float b) {
    return (uint)f2b(a) | ((uint)f2b(b) << 16);
}

// ================= CSR build: radix partition, no global atomics =================
__global__ __launch_bounds__(256) void k_hist(const int* __restrict__ dst,
                                              int* __restrict__ hist) {
    __shared__ int lh[NBUK];
    int t = threadIdx.x, b = blockIdx.x;
    for (int i = t; i < NBUK; i += 256) lh[i] = 0;
    __syncthreads();
    int e0 = b * CHUNK;
    for (int e = e0 + t; e < e0 + CHUNK; e += 256)
        atomicAdd(&lh[dst[e] >> BUCKET_SH], 1);
    __syncthreads();
    for (int i = t; i < NBUK; i += 256) hist[i * NBLK + b] = lh[i];
}

__global__ __launch_bounds__(256) void k_scan1(int* __restrict__ hist, int* __restrict__ psums) {
    __shared__ int sh[256];
    int t = threadIdx.x;
    int i = blockIdx.x * 256 + t;
    int v = hist[i];
    sh[t] = v; __syncthreads();
    for (int off = 1; off < 256; off <<= 1) {
        int a = (t >= off) ? sh[t - off] : 0;
        __syncthreads();
        sh[t] += a;
        __syncthreads();
    }
    hist[i] = sh[t] - v;
    if (t == 255) psums[blockIdx.x] = sh[255];
}

__global__ __launch_bounds__(1024) void k_scan2(int* __restrict__ psums) {
    __shared__ int sh[1024];
    int t = threadIdx.x;
    int v = (t < SCAN_BLKS) ? psums[t] : 0;
    sh[t] = v; __syncthreads();
    for (int off = 1; off < 1024; off <<= 1) {
        int a = (t >= off) ? sh[t - off] : 0;
        __syncthreads();
        sh[t] += a;
        __syncthreads();
    }
    if (t < SCAN_BLKS) psums[t] = sh[t] - v;
}

__global__ __launch_bounds__(256) void k_partition(const int* __restrict__ src,
                                                   const int* __restrict__ dst,
                                                   const int* __restrict__ hist,
                                                   const int* __restrict__ psums,
                                                   uint* __restrict__ tmp) {
    __shared__ int lcur[NBUK];
    int t = threadIdx.x, b = blockIdx.x;
    for (int i = t; i < NBUK; i += 256) lcur[i] = hist[i * NBLK + b] + psums[i];
    __syncthreads();
    int e0 = b * CHUNK;
    for (int e = e0 + t; e < e0 + CHUNK; e += 256) {
        int d = dst[e];
        int bk = d >> BUCKET_SH;
        int pos = atomicAdd(&lcur[bk], 1);
        tmp[pos] = (uint)src[e] | ((uint)(d & ((1 << BUCKET_SH) - 1)) << 17);
    }
}

__global__ __launch_bounds__(256) void k_bucket_fill(const uint* __restrict__ tmp,
                                                     const int* __restrict__ psums,
                                                     int* __restrict__ row_ptr,
                                                     int* __restrict__ csr) {
    __shared__ int hist[128], inc[128], cur[128];
    int b = blockIdx.x, t = threadIdx.x;
    int base = psums[b];
    int end  = (b + 1 < NBUK) ? psums[b + 1] : N_EDGES;
    int nb = end - base;
    int lo = b << BUCKET_SH;
    const uint* bt = tmp + base;

    if (t < 128) hist[t] = 0;
    __syncthreads();
    for (int i = t; i < nb; i += 256)
        atomicAdd(&hist[bt[i] >> 17], 1);
    __syncthreads();
    if (t < 128) inc[t] = hist[t];
    __syncthreads();
    for (int offs = 1; offs < 128; offs <<= 1) {
        int a = (t < 128 && t >= offs) ? inc[t - offs] : 0;
        __syncthreads();
        if (t < 128) inc[t] += a;
        __syncthreads();
    }
    if (t < 128) {
        int node = lo + t;
        if (node < N_NODES) row_ptr[node] = base + inc[t] - hist[t];
        cur[t] = 0;
    }
    if (b == NBUK - 1 && t == 0) row_ptr[N_NODES] = base + nb;
    __syncthreads();
    for (int i = t; i < nb; i += 256) {
        uint u = bt[i];
        int dl = u >> 17;
        int s = (int)(u & 0x1ffffu);
        int p = atomicAdd(&cur[dl], 1);
        csr[base + (inc[dl] - hist[dl]) + p] = s;
    }
}

// ================= fp32 -> bf16: x and all weights =================
__global__ void k_conv(const float* __restrict__ x, const float* __restrict__ W1,
                       const float* __restrict__ W2, const float* __restrict__ l1W,
                       ushort* __restrict__ hbf, ushort* __restrict__ wbf) {
    int i = blockIdx.x * 256 + threadIdx.x;
    const int n4x = N_NODES * D / 4;               // 3,200,000
    if (i < n4x) {
        float4 v = ((const float4*)x)[i];
        uint2 u;
        u.x = pack2(v.x, v.y);
        u.y = pack2(v.z, v.w);
        ((uint2*)hbf)[i] = u;
    } else {
        int k = i - n4x;                           // float4 index into weights
        const float* srcp;
        ushort* dstp;
        if (k < 12288)      { srcp = W1 + k * 4;            dstp = wbf + k * 4; }
        else if (k < 24576) { srcp = W2 + (k - 12288) * 4;  dstp = wbf + 49152 + (k - 12288) * 4; }
        else if (k < 28672) { srcp = l1W + (k - 24576) * 4; dstp = wbf + 98304 + (k - 24576) * 4; }
        else return;
        float4 v = *(const float4*)srcp;
        ushort4 u;
        u.x = f2b(v.x); u.y = f2b(v.y); u.z = f2b(v.z); u.w = f2b(v.w);
        *(ushort4*)dstp = u;
    }
}

// ================= aggregation (4B lanes, 1 row/instr, 8-deep) =================
__global__ __launch_bounds__(256) void k_aggregate(const ushort* __restrict__ hbf,
                                                   const int* __restrict__ row_ptr,
                                                   const int* __restrict__ csr,
                                                   ushort* __restrict__ outbf) {
    int node = blockIdx.x * 4 + (threadIdx.x >> 6);
    int lane = threadIdx.x & 63;
    const uint* hp = (const uint*)hbf;
    uint self = hp[(size_t)node * 64 + lane];
    float ax = b2f(self & 0xffffu), ay = b2f(self >> 16);
    int e0 = row_ptr[node], e1 = row_ptr[node + 1];
    int e = e0;
    for (; e + 7 < e1; e += 8) {
        uint v0 = hp[(size_t)csr[e]     * 64 + lane];
        uint v1 = hp[(size_t)csr[e + 1] * 64 + lane];
        uint v2 = hp[(size_t)csr[e + 2] * 64 + lane];
        uint v3 = hp[(size_t)csr[e + 3] * 64 + lane];
        uint v4 = hp[(size_t)csr[e + 4] * 64 + lane];
        uint v5 = hp[(size_t)csr[e + 5] * 64 + lane];
        uint v6 = hp[(size_t)csr[e + 6] * 64 + lane];
        uint v7 = hp[(size_t)csr[e + 7] * 64 + lane];
        ax += b2f(v0 & 0xffffu); ay += b2f(v0 >> 16);
        ax += b2f(v1 & 0xffffu); ay += b2f(v1 >> 16);
        ax += b2f(v2 & 0xffffu); ay += b2f(v2 >> 16);
        ax += b2f(v3 & 0xffffu); ay += b2f(v3 >> 16);
        ax += b2f(v4 & 0xffffu); ay += b2f(v4 >> 16);
        ax += b2f(v5 & 0xffffu); ay += b2f(v5 >> 16);
        ax += b2f(v6 & 0xffffu); ay += b2f(v6 >> 16);
        ax += b2f(v7 & 0xffffu); ay += b2f(v7 >> 16);
    }
    for (; e < e1; ++e) {
        uint v = hp[(size_t)csr[e] * 64 + lane];
        ax += b2f(v & 0xffffu); ay += b2f(v >> 16);
    }
    __builtin_nontemporal_store(pack2(ax, ay), (uint*)outbf + (size_t)node * 64 + lane);
}

// ================= fused GIN layer: gemm1 + BN stats + grid barrier + BN + gemm2 =====
// 782 blocks x 256 thr, 4 blocks/CU (36KB LDS, launch_bounds) -> all blocks co-resident.
__global__ __launch_bounds__(256, 4) void k_layer(const ushort* __restrict__ aggin,
                                                  const ushort* __restrict__ W1bf,
                                                  const float* __restrict__ b1,
                                                  const float* __restrict__ gamma,
                                                  const float* __restrict__ beta,
                                                  const ushort* __restrict__ W2bf,
                                                  const float* __restrict__ b2,
                                                  ushort* __restrict__ hout,
                                                  float* __restrict__ gsum,
                                                  float* __restrict__ gsq,
                                                  int* __restrict__ ctr) {
    __shared__ ushort sA[128 * LDA];          // A tile; reused for BN(z) and for out bounce
    __shared__ float sb1[128], sb2[128], lsum[128], lsq[128];

    int t = threadIdx.x;
    int r0 = blockIdx.x * 128;

    if (t < 128) {
        sb1[t] = b1[t]; sb2[t] = b2[t];
        lsum[t] = 0.f; lsq[t] = 0.f;
    }

    // ---- stage A tile ----
    for (int idx = t; idx < 128 * 16; idx += 256) {
        int r = idx >> 4, c8 = (idx & 15) << 3;
        int rr = r0 + r;
        u32x4 v = (u32x4){0u, 0u, 0u, 0u};
        if (rr < N_NODES) v = __builtin_nontemporal_load((const u32x4*)(aggin + (size_t)rr * 128 + c8));
        *(u32x4*)&sA[r * LDA + c8] = v;
    }
    __syncthreads();

    int lane = t & 63, wid = t >> 6;
    int rl = lane & 15, g = lane >> 4;
    int wr = wid >> 1, wc = wid & 1;

    // ---- gemm1: z = A @ W1.T ----
    f32x4 acc[4][4];
#pragma unroll
    for (int i = 0; i < 4; ++i)
#pragma unroll
        for (int j = 0; j < 4; ++j) acc[i][j] = (f32x4){0.f, 0.f, 0.f, 0.f};

#pragma unroll
    for (int ks = 0; ks < 4; ++ks) {
        int koff = ks * 32 + g * 8;
        bf16x8 a[4], b[4];
#pragma unroll
        for (int ni = 0; ni < 4; ++ni)
            b[ni] = *(const bf16x8*)&W1bf[(size_t)(wc * 64 + ni * 16 + rl) * 128 + koff];
#pragma unroll
        for (int mi = 0; mi < 4; ++mi)
            a[mi] = *(const bf16x8*)&sA[(wr * 64 + mi * 16 + rl) * LDA + koff];
#pragma unroll
        for (int mi = 0; mi < 4; ++mi)
#pragma unroll
            for (int ni = 0; ni < 4; ++ni)
                acc[mi][ni] = __builtin_amdgcn_mfma_f32_16x16x32_bf16(a[mi], b[ni], acc[mi][ni], 0, 0, 0);
    }

    // ---- column stats of z (= acc + b1), pre-relu ----
    float bn1[4], ssum[4], ssq[4];
#pragma unroll
    for (int ni = 0; ni < 4; ++ni) {
        bn1[ni] = sb1[wc * 64 + ni * 16 + rl];
        ssum[ni] = 0.f; ssq[ni] = 0.f;
    }
#pragma unroll
    for (int mi = 0; mi < 4; ++mi) {
        int orow = r0 + wr * 64 + mi * 16 + g * 4;
#pragma unroll
        for (int j = 0; j < 4; ++j) {
            if (orow + j < N_NODES) {
#pragma unroll
                for (int ni = 0; ni < 4; ++ni) {
                    float o = acc[mi][ni][j] + bn1[ni];
                    ssum[ni] += o; ssq[ni] += o * o;
                }
            }
        }
    }
#pragma unroll
    for (int ni = 0; ni < 4; ++ni) {
        float s = ssum[ni], q = ssq[ni];
        s += __shfl_xor(s, 16, 64); q += __shfl_xor(q, 16, 64);
        s += __shfl_xor(s, 32, 64); q += __shfl_xor(q, 32, 64);
        if (g == 0) {
            int col = wc * 64 + ni * 16 + rl;
            atomicAdd(&lsum[col], s);
            atomicAdd(&lsq[col], q);
        }
    }
    __syncthreads();
    if (t < 128) {
        atomicAdd(&gsum[t], lsum[t]);
        atomicAdd(&gsq[t], lsq[t]);
    }
    __syncthreads();   // drains vmcnt: all this block's global atomics complete

    // ---- grid barrier (all 782 blocks co-resident by construction) ----
    if (t == 0) {
        __hip_atomic_fetch_add(ctr, 1, __ATOMIC_RELEASE, __HIP_MEMORY_SCOPE_AGENT);
        while (__hip_atomic_load(ctr, __ATOMIC_ACQUIRE, __HIP_MEMORY_SCOPE_AGENT) < NBUK)
            __builtin_amdgcn_s_sleep(32);
    }
    __syncthreads();

    // ---- inline BN finalize for this thread's 4 columns ----
    float scl[4], shf[4];
#pragma unroll
    for (int ni = 0; ni < 4; ++ni) {
        int col = wc * 64 + ni * 16 + rl;
        float s = __hip_atomic_load(&gsum[col], __ATOMIC_RELAXED, __HIP_MEMORY_SCOPE_AGENT);
        float q = __hip_atomic_load(&gsq[col],  __ATOMIC_RELAXED, __HIP_MEMORY_SCOPE_AGENT);
        float mu = s * (1.f / N_NODES);
        float var = q * (1.f / N_NODES) - mu * mu;
        float rstd = rsqrtf(var + BN_EPS);
        float sc = rstd * gamma[col];
        scl[ni] = sc;
        shf[ni] = beta[col] - mu * sc;
    }

    // ---- apply BN+relu to fp32 z, write bf16 back into sA ----
#pragma unroll
    for (int mi = 0; mi < 4; ++mi) {
        int rowl = wr * 64 + mi * 16 + g * 4;
#pragma unroll
        for (int j = 0; j < 4; ++j) {
#pragma unroll
            for (int ni = 0; ni < 4; ++ni) {
                int ocol = wc * 64 + ni * 16 + rl;
                float o = acc[mi][ni][j] + bn1[ni];
                float v = fmaxf(fmaf(o, scl[ni], shf[ni]), 0.f);
                sA[(rowl + j) * LDA + ocol] = f2b(v);
            }
        }
    }
    __syncthreads();

    // ---- gemm2: h' = relu( BN(z) @ W2.T + b2 ) ----
    f32x4 acc2[4][4];
#pragma unroll
    for (int i = 0; i < 4; ++i)
#pragma unroll
        for (int j = 0; j < 4; ++j) acc2[i][j] = (f32x4){0.f, 0.f, 0.f, 0.f};

#pragma unroll
    for (int ks = 0; ks < 4; ++ks) {
        int koff = ks * 32 + g * 8;
        bf16x8 a[4], b[4];
#pragma unroll
        for (int ni = 0; ni < 4; ++ni)
            b[ni] = *(const bf16x8*)&W2bf[(size_t)(wc * 64 + ni * 16 + rl) * 128 + koff];
#pragma unroll
        for (int mi = 0; mi < 4; ++mi)
            a[mi] = *(const bf16x8*)&sA[(wr * 64 + mi * 16 + rl) * LDA + koff];
#pragma unroll
        for (int mi = 0; mi < 4; ++mi)
#pragma unroll
            for (int ni = 0; ni < 4; ++ni)
                acc2[mi][ni] = __builtin_amdgcn_mfma_f32_16x16x32_bf16(a[mi], b[ni], acc2[mi][ni], 0, 0, 0);
    }
    __syncthreads();   // all MFMA reads of sA done -> safe to overwrite

    float bn2[4];
#pragma unroll
    for (int ni = 0; ni < 4; ++ni) bn2[ni] = sb2[wc * 64 + ni * 16 + rl];
#pragma unroll
    for (int mi = 0; mi < 4; ++mi) {
        int rowl = wr * 64 + mi * 16 + g * 4;
#pragma unroll
        for (int j = 0; j < 4; ++j) {
#pragma unroll
            for (int ni = 0; ni < 4; ++ni) {
                int ocol = wc * 64 + ni * 16 + rl;
                float o = fmaxf(acc2[mi][ni][j] + bn2[ni], 0.f);
                sA[(rowl + j) * LDA + ocol] = f2b(o);
            }
        }
    }
    __syncthreads();

    // ---- coalesced output copy ----
    for (int idx = t; idx < 128 * 16; idx += 256) {
        int r = idx >> 4, c8 = (idx & 15) << 3;
        int rr = r0 + r;
        if (rr < N_NODES) {
            u32x4 v = *(const u32x4*)&sA[r * LDA + c8];
            __builtin_nontemporal_store(v, (u32x4*)(hout + (size_t)rr * 128 + c8));
        }
    }
}

// ================= fused head: out = sigmoid(relu(h@l1W.T+l1b) @ l2W.T + l2b) ========
__global__ __launch_bounds__(256, 3) void k_head(const ushort* __restrict__ hbf,
                                                 const ushort* __restrict__ l1bf,
                                                 const float* __restrict__ b1f,
                                                 const float* __restrict__ W2,
                                                 const float* __restrict__ b2f_,
                                                 float* __restrict__ out) {
    __shared__ ushort sA[128 * LDA];          // h tile, later reused as z^T tile
    __shared__ float sbias[128];
    __shared__ float w2s[NCLASS * 128];
    __shared__ float b2s[NCLASS];

    int t = threadIdx.x;
    int r0 = blockIdx.x * 128;

    if (t < 128) sbias[t] = b1f[t];
    for (int idx = t; idx < (NCLASS * 128) / 4; idx += 256)
        *(float4*)&w2s[idx * 4] = *(const float4*)(W2 + idx * 4);
    if (t < NCLASS) b2s[t] = b2f_[t];

    for (int idx = t; idx < 128 * 16; idx += 256) {
        int r = idx >> 4, c8 = (idx & 15) << 3;
        int rr = r0 + r;
        u32x4 v = (u32x4){0u, 0u, 0u, 0u};
        if (rr < N_NODES) v = __builtin_nontemporal_load((const u32x4*)(hbf + (size_t)rr * 128 + c8));
        *(u32x4*)&sA[r * LDA + c8] = v;
    }
    __syncthreads();

    int lane = t & 63, wid = t >> 6;
    int rl = lane & 15, g = lane >> 4;
    int wr = wid >> 1, wc = wid & 1;

    f32x4 acc[4][4];
#pragma unroll
    for (int i = 0; i < 4; ++i)
#pragma unroll
        for (int j = 0; j < 4; ++j) acc[i][j] = (f32x4){0.f, 0.f, 0.f, 0.f};

#pragma unroll
    for (int ks = 0; ks < 4; ++ks) {
        int koff = ks * 32 + g * 8;
        bf16x8 a[4], b[4];
#pragma unroll
        for (int ni = 0; ni < 4; ++ni)
            b[ni] = *(const bf16x8*)&l1bf[(size_t)(wc * 64 + ni * 16 + rl) * 128 + koff];
#pragma unroll
        for (int mi = 0; mi < 4; ++mi)
            a[mi] = *(const bf16x8*)&sA[(wr * 64 + mi * 16 + rl) * LDA + koff];
#pragma unroll
        for (int mi = 0; mi < 4; ++mi)
#pragma unroll
            for (int ni = 0; ni < 4; ++ni)
                acc[mi][ni] = __builtin_amdgcn_mfma_f32_16x16x32_bf16(a[mi], b[ni], acc[mi][ni], 0, 0, 0);
    }

    __syncthreads();   // all waves done reading sA -> safe to overwrite with z^T

    float bn[4];
#pragma unroll
    for (int ni = 0; ni < 4; ++ni) bn[ni] = sbias[wc * 64 + ni * 16 + rl];
#pragma unroll
    for (int mi = 0; mi < 4; ++mi) {
        int rowl = wr * 64 + mi * 16 + g * 4;
#pragma unroll
        for (int j = 0; j < 4; ++j) {
#pragma unroll
            for (int ni = 0; ni < 4; ++ni) {
                int ocol = wc * 64 + ni * 16 + rl;
                float o = fmaxf(acc[mi][ni][j] + bn[ni], 0.f);
                sA[ocol * LDA + rowl + j] = f2b(o);   // z^T: [col][row]
            }
        }
    }
    __syncthreads();

    int row = t & 127, ch = t >> 7;
    float acc2[5] = {0.f, 0.f, 0.f, 0.f, 0.f};
    const float* w2p = &w2s[ch * 5 * 128];
#pragma unroll 4
    for (int k = 0; k < 128; ++k) {
        float v = b2f(sA[k * LDA + row]);
#pragma unroll
        for (int c = 0; c < 5; ++c)
            acc2[c] = fmaf(v, w2p[c * 128 + k], acc2[c]);
    }
    int rr = r0 + row;
    if (rr < N_NODES) {
#pragma unroll
        for (int c = 0; c < 5; ++c) {
            float z = acc2[c] + b2s[ch * 5 + c];
            out[(size_t)rr * NCLASS + ch * 5 + c] = 1.f / (1.f + expf(-z));
        }
    }
}

// ================= launcher =================
extern "C" void kernel_launch(void* const* d_in, const int* in_sizes, int n_in,
                              void* d_out, int out_size, void* d_ws, size_t ws_size,
                              hipStream_t stream) {
    const float* x     = (const float*)d_in[0];
    const int*   ei    = (const int*)d_in[1];
    const float* W1    = (const float*)d_in[2];
    const float* b1    = (const float*)d_in[3];
    const float* gamma = (const float*)d_in[4];
    const float* beta  = (const float*)d_in[5];
    const float* W2    = (const float*)d_in[6];
    const float* b2    = (const float*)d_in[7];
    const float* l1W   = (const float*)d_in[8];
    const float* l1b   = (const float*)d_in[9];
    const float* l2W   = (const float*)d_in[10];
    const float* l2b   = (const float*)d_in[11];
    float* out = (float*)d_out;

    char* w = (char*)d_ws;
    ushort* hbf    = (ushort*)(w);                   // 25,600,000 B
    ushort* aggout = (ushort*)(w + 25600000);        // 25,600,000 B
    int*   row_ptr = (int*)   (w + 51200000);        // 400,004 B (reserve 400,640)
    int*   csr     = (int*)   (w + 51600640);        // 6,400,000 B
    uint*  tmp     = (uint*)  (w + 58000640);        // 6,400,000 B
    int*   hist    = (int*)   (w + 64400640);        // 800,768 (reserve 801,280)
    int*   psums   = (int*)   (w + 65201920);        // reserve 4,096
    float* gstats  = (float*) (w + 65206016);        // 3 layers x 256 floats = 3072 B
    int*   ctrs    = (int*)   (w + 65209088);        // 3 ints (memset together w/ gstats)
    ushort* wbf    = (ushort*)(w + 65209472);        // 229,376 B
    ushort* w1bf   = wbf;                            // [3][128][128]
    ushort* w2bf   = wbf + 49152;                    // [3][128][128]
    ushort* l1bf   = wbf + 98304;                    // [128][128]

    const int* src = ei;
    const int* dst = ei + N_EDGES;

    // zero gstats (3072 B) + ctrs (12 B) in one memset
    (void)hipMemsetAsync(gstats, 0, 3072 + 64, stream);

    // ---- CSR build (radix partition, zero global atomics) ----
    k_hist<<<NBLK, 256, 0, stream>>>(dst, hist);
    k_scan1<<<SCAN_BLKS, 256, 0, stream>>>(hist, psums);
    k_scan2<<<1, 1024, 0, stream>>>(psums);
    k_partition<<<NBLK, 256, 0, stream>>>(src, dst, hist, psums, tmp);
    k_bucket_fill<<<NBUK, 256, 0, stream>>>(tmp, psums, row_ptr, csr);

    // ---- x + weights -> bf16 ----
    const int CONV_NB = (N_NODES * D / 4 + 28672 + 255) / 256;
    k_conv<<<CONV_NB, 256, 0, stream>>>(x, W1, W2, l1W, hbf, wbf);

    // ---- 3 fused GIN layers ----
    for (int l = 0; l < NLAYERS; ++l) {
        k_aggregate<<<N_NODES / 4, 256, 0, stream>>>(hbf, row_ptr, csr, aggout);
        k_layer<<<NBUK, 256, 0, stream>>>(aggout, w1bf + l * D * D, b1 + l * D,
                                          gamma + l * D, beta + l * D,
                                          w2bf + l * D * D, b2 + l * D,
                                          hbf, gstats + l * 256, gstats + l * 256 + 128,
                                          ctrs + l);
    }

    // ---- fused head ----
    k_head<<<NBUK, 256, 0, stream>>>(hbf, l1bf, l1b, l2W, l2b, out);
}

// Round 11
// 476.911 us; speedup vs baseline: 1.2269x; 1.2269x over previous
//
#include <hip/hip_runtime.h>
#include <math.h>

#define N_NODES 100000
#define N_EDGES 1600000
#define D 128
#define NCLASS 10
#define NLAYERS 3
#define BN_EPS 1e-5f

#define LDA 136        // padded LDS row stride in bf16 elems
#define BUCKET_SH 7    // 128 nodes per bucket
#define NBUK 782       // ceil(100000/128)
#define NBLK 256       // partition blocks (== scan chunk size -> psums[i] = bucket i base)
#define CHUNK 6250     // N_EDGES / NBLK (exact)
#define SCAN_BLKS NBUK

typedef __attribute__((ext_vector_type(8))) short bf16x8;
typedef __attribute__((ext_vector_type(4))) float f32x4;
typedef __attribute__((ext_vector_type(4))) uint u32x4;

__device__ __forceinline__ ushort f2b(float x) {          // RNE fp32 -> bf16
    uint u = __float_as_uint(x);
    return (ushort)((u + 0x7fffu + ((u >> 16) & 1u)) >> 16);
}
__device__ __forceinline__ float b2f(uint u) {            // bf16 bits -> fp32 (exact)
    return __uint_as_float(u << 16);
}
__device__ __forceinline__ uint pack2(float a, float b) {
    return (uint)f2b(a) | ((uint)f2b(b) << 16);
}

// ================= CSR build: radix partition, no global atomics =================
__global__ __launch_bounds__(256) void k_hist(const int* __restrict__ dst,
                                              int* __restrict__ hist) {
    __shared__ int lh[NBUK];
    int t = threadIdx.x, b = blockIdx.x;
    for (int i = t; i < NBUK; i += 256) lh[i] = 0;
    __syncthreads();
    int e0 = b * CHUNK;
    for (int e = e0 + t; e < e0 + CHUNK; e += 256)
        atomicAdd(&lh[dst[e] >> BUCKET_SH], 1);
    __syncthreads();
    for (int i = t; i < NBUK; i += 256) hist[i * NBLK + b] = lh[i];
}

__global__ __launch_bounds__(256) void k_scan1(int* __restrict__ hist, int* __restrict__ psums) {
    __shared__ int sh[256];
    int t = threadIdx.x;
    int i = blockIdx.x * 256 + t;
    int v = hist[i];
    sh[t] = v; __syncthreads();
    for (int off = 1; off < 256; off <<= 1) {
        int a = (t >= off) ? sh[t - off] : 0;
        __syncthreads();
        sh[t] += a;
        __syncthreads();
    }
    hist[i] = sh[t] - v;
    if (t == 255) psums[blockIdx.x] = sh[255];
}

__global__ __launch_bounds__(1024) void k_scan2(int* __restrict__ psums) {
    __shared__ int sh[1024];
    int t = threadIdx.x;
    int v = (t < SCAN_BLKS) ? psums[t] : 0;
    sh[t] = v; __syncthreads();
    for (int off = 1; off < 1024; off <<= 1) {
        int a = (t >= off) ? sh[t - off] : 0;
        __syncthreads();
        sh[t] += a;
        __syncthreads();
    }
    if (t < SCAN_BLKS) psums[t] = sh[t] - v;
}

__global__ __launch_bounds__(256) void k_partition(const int* __restrict__ src,
                                                   const int* __restrict__ dst,
                                                   const int* __restrict__ hist,
                                                   const int* __restrict__ psums,
                                                   uint* __restrict__ tmp) {
    __shared__ int lcur[NBUK];
    int t = threadIdx.x, b = blockIdx.x;
    for (int i = t; i < NBUK; i += 256) lcur[i] = hist[i * NBLK + b] + psums[i];
    __syncthreads();
    int e0 = b * CHUNK;
    for (int e = e0 + t; e < e0 + CHUNK; e += 256) {
        int d = dst[e];
        int bk = d >> BUCKET_SH;
        int pos = atomicAdd(&lcur[bk], 1);
        tmp[pos] = (uint)src[e] | ((uint)(d & ((1 << BUCKET_SH) - 1)) << 17);
    }
}

__global__ __launch_bounds__(256) void k_bucket_fill(const uint* __restrict__ tmp,
                                                     const int* __restrict__ psums,
                                                     int* __restrict__ row_ptr,
                                                     int* __restrict__ csr) {
    __shared__ int hist[128], inc[128], cur[128];
    int b = blockIdx.x, t = threadIdx.x;
    int base = psums[b];
    int end  = (b + 1 < NBUK) ? psums[b + 1] : N_EDGES;
    int nb = end - base;
    int lo = b << BUCKET_SH;
    const uint* bt = tmp + base;

    if (t < 128) hist[t] = 0;
    __syncthreads();
    for (int i = t; i < nb; i += 256)
        atomicAdd(&hist[bt[i] >> 17], 1);
    __syncthreads();
    if (t < 128) inc[t] = hist[t];
    __syncthreads();
    for (int offs = 1; offs < 128; offs <<= 1) {
        int a = (t < 128 && t >= offs) ? inc[t - offs] : 0;
        __syncthreads();
        if (t < 128) inc[t] += a;
        __syncthreads();
    }
    if (t < 128) {
        int node = lo + t;
        if (node < N_NODES) row_ptr[node] = base + inc[t] - hist[t];
        cur[t] = 0;
    }
    if (b == NBUK - 1 && t == 0) row_ptr[N_NODES] = base + nb;
    __syncthreads();
    for (int i = t; i < nb; i += 256) {
        uint u = bt[i];
        int dl = u >> 17;
        int s = (int)(u & 0x1ffffu);
        int p = atomicAdd(&cur[dl], 1);
        csr[base + (inc[dl] - hist[dl]) + p] = s;
    }
}

// ================= fp32 -> bf16: x and all weights =================
__global__ void k_conv(const float* __restrict__ x, const float* __restrict__ W1,
                       const float* __restrict__ W2, const float* __restrict__ l1W,
                       ushort* __restrict__ hbf, ushort* __restrict__ wbf) {
    int i = blockIdx.x * 256 + threadIdx.x;
    const int n4x = N_NODES * D / 4;               // 3,200,000
    if (i < n4x) {
        float4 v = ((const float4*)x)[i];
        uint2 u;
        u.x = pack2(v.x, v.y);
        u.y = pack2(v.z, v.w);
        ((uint2*)hbf)[i] = u;
    } else {
        int k = i - n4x;                           // float4 index into weights
        const float* srcp;
        ushort* dstp;
        if (k < 12288)      { srcp = W1 + k * 4;            dstp = wbf + k * 4; }
        else if (k < 24576) { srcp = W2 + (k - 12288) * 4;  dstp = wbf + 49152 + (k - 12288) * 4; }
        else if (k < 28672) { srcp = l1W + (k - 24576) * 4; dstp = wbf + 98304 + (k - 24576) * 4; }
        else return;
        float4 v = *(const float4*)srcp;
        ushort4 u;
        u.x = f2b(v.x); u.y = f2b(v.y); u.z = f2b(v.z); u.w = f2b(v.w);
        *(ushort4*)dstp = u;
    }
}

// ================= aggregation (4B lanes, 1 row/instr, 8-deep) =================
__global__ __launch_bounds__(256) void k_aggregate(const ushort* __restrict__ hbf,
                                                   const int* __restrict__ row_ptr,
                                                   const int* __restrict__ csr,
                                                   ushort* __restrict__ outbf) {
    int node = blockIdx.x * 4 + (threadIdx.x >> 6);
    int lane = threadIdx.x & 63;
    const uint* hp = (const uint*)hbf;
    uint self = hp[(size_t)node * 64 + lane];
    float ax = b2f(self & 0xffffu), ay = b2f(self >> 16);
    int e0 = row_ptr[node], e1 = row_ptr[node + 1];
    int e = e0;
    for (; e + 7 < e1; e += 8) {
        uint v0 = hp[(size_t)csr[e]     * 64 + lane];
        uint v1 = hp[(size_t)csr[e + 1] * 64 + lane];
        uint v2 = hp[(size_t)csr[e + 2] * 64 + lane];
        uint v3 = hp[(size_t)csr[e + 3] * 64 + lane];
        uint v4 = hp[(size_t)csr[e + 4] * 64 + lane];
        uint v5 = hp[(size_t)csr[e + 5] * 64 + lane];
        uint v6 = hp[(size_t)csr[e + 6] * 64 + lane];
        uint v7 = hp[(size_t)csr[e + 7] * 64 + lane];
        ax += b2f(v0 & 0xffffu); ay += b2f(v0 >> 16);
        ax += b2f(v1 & 0xffffu); ay += b2f(v1 >> 16);
        ax += b2f(v2 & 0xffffu); ay += b2f(v2 >> 16);
        ax += b2f(v3 & 0xffffu); ay += b2f(v3 >> 16);
        ax += b2f(v4 & 0xffffu); ay += b2f(v4 >> 16);
        ax += b2f(v5 & 0xffffu); ay += b2f(v5 >> 16);
        ax += b2f(v6 & 0xffffu); ay += b2f(v6 >> 16);
        ax += b2f(v7 & 0xffffu); ay += b2f(v7 >> 16);
    }
    for (; e < e1; ++e) {
        uint v = hp[(size_t)csr[e] * 64 + lane];
        ax += b2f(v & 0xffffu); ay += b2f(v >> 16);
    }
    __builtin_nontemporal_store(pack2(ax, ay), (uint*)outbf + (size_t)node * 64 + lane);
}

// ================= MFMA GEMM: A from LDS, W(bf16) direct from global =================
// PRE: 0 = copy bf16 A; 2 = BN finalize from gsum/gsq in prologue, apply relu(a*sc+sf).
// POST: 1 = relu.  STATS: fused column sum/sumsq -> gsum/gsq atomics.
// Output bf16 via LDS-bounce coalesced stores.
template <int PRE, int POST, int STATS>
__global__ __launch_bounds__(256, 4) void k_gemm(const ushort* __restrict__ inA,
                                                 const ushort* __restrict__ Wbf,
                                                 const float* __restrict__ bias,
                                                 const float* __restrict__ gamma,
                                                 const float* __restrict__ beta,
                                                 ushort* __restrict__ outp,
                                                 float* __restrict__ gsum,
                                                 float* __restrict__ gsq,
                                                 int nrows) {
    __shared__ ushort sA[128 * LDA];
    __shared__ float sbias[128];
    __shared__ float lsum[128], lsq[128];
    __shared__ float sscale[128], sshift[128];

    int t = threadIdx.x;
    int r0 = blockIdx.x * 128;

    if (t < 128) {
        sbias[t] = bias[t];
        if (STATS) { lsum[t] = 0.f; lsq[t] = 0.f; }
        if (PRE == 2) {
            float s = gsum[t], q = gsq[t];
            float mu = s * (1.f / N_NODES);
            float var = q * (1.f / N_NODES) - mu * mu;
            float rstd = rsqrtf(var + BN_EPS);
            float sc = rstd * gamma[t];
            sscale[t] = sc;
            sshift[t] = beta[t] - mu * sc;
        }
    }
    if (PRE == 2) __syncthreads();   // stage loop consumes sscale/sshift

    for (int idx = t; idx < 128 * 16; idx += 256) {
        int r = idx >> 4, c8 = (idx & 15) << 3;
        int rr = r0 + r;
        u32x4 v = (u32x4){0u, 0u, 0u, 0u};
        if (rr < nrows) v = __builtin_nontemporal_load((const u32x4*)(inA + (size_t)rr * 128 + c8));
        if (PRE == 2) {
            float f0 = b2f(v.x & 0xffffu), f1 = b2f(v.x >> 16);
            float f2 = b2f(v.y & 0xffffu), f3 = b2f(v.y >> 16);
            float f4 = b2f(v.z & 0xffffu), f5 = b2f(v.z >> 16);
            float f6 = b2f(v.w & 0xffffu), f7 = b2f(v.w >> 16);
            float4 sc0 = *(const float4*)&sscale[c8];
            float4 sc1 = *(const float4*)&sscale[c8 + 4];
            float4 sf0 = *(const float4*)&sshift[c8];
            float4 sf1 = *(const float4*)&sshift[c8 + 4];
            f0 = fmaxf(fmaf(f0, sc0.x, sf0.x), 0.f);
            f1 = fmaxf(fmaf(f1, sc0.y, sf0.y), 0.f);
            f2 = fmaxf(fmaf(f2, sc0.z, sf0.z), 0.f);
            f3 = fmaxf(fmaf(f3, sc0.w, sf0.w), 0.f);
            f4 = fmaxf(fmaf(f4, sc1.x, sf1.x), 0.f);
            f5 = fmaxf(fmaf(f5, sc1.y, sf1.y), 0.f);
            f6 = fmaxf(fmaf(f6, sc1.z, sf1.z), 0.f);
            f7 = fmaxf(fmaf(f7, sc1.w, sf1.w), 0.f);
            v.x = pack2(f0, f1); v.y = pack2(f2, f3);
            v.z = pack2(f4, f5); v.w = pack2(f6, f7);
        }
        *(u32x4*)&sA[r * LDA + c8] = v;
    }
    __syncthreads();

    int lane = t & 63, wid = t >> 6;
    int rl = lane & 15, g = lane >> 4;
    int wr = wid >> 1, wc = wid & 1;

    f32x4 acc[4][4];
#pragma unroll
    for (int i = 0; i < 4; ++i)
#pragma unroll
        for (int j = 0; j < 4; ++j) acc[i][j] = (f32x4){0.f, 0.f, 0.f, 0.f};

#pragma unroll
    for (int ks = 0; ks < 4; ++ks) {
        int koff = ks * 32 + g * 8;
        bf16x8 a[4], b[4];
#pragma unroll
        for (int ni = 0; ni < 4; ++ni)
            b[ni] = *(const bf16x8*)&Wbf[(size_t)(wc * 64 + ni * 16 + rl) * 128 + koff];
#pragma unroll
        for (int mi = 0; mi < 4; ++mi)
            a[mi] = *(const bf16x8*)&sA[(wr * 64 + mi * 16 + rl) * LDA + koff];
#pragma unroll
        for (int mi = 0; mi < 4; ++mi)
#pragma unroll
            for (int ni = 0; ni < 4; ++ni)
                acc[mi][ni] = __builtin_amdgcn_mfma_f32_16x16x32_bf16(a[mi], b[ni], acc[mi][ni], 0, 0, 0);
    }
    __syncthreads();   // all MFMA reads of sA complete -> sA reusable as out bounce

    float bn[4], ssum[4], ssq[4];
#pragma unroll
    for (int ni = 0; ni < 4; ++ni) {
        bn[ni] = sbias[wc * 64 + ni * 16 + rl];
        ssum[ni] = 0.f; ssq[ni] = 0.f;
    }

#pragma unroll
    for (int mi = 0; mi < 4; ++mi) {
        int rowl = wr * 64 + mi * 16 + g * 4;
#pragma unroll
        for (int j = 0; j < 4; ++j) {
            bool inb = (r0 + rowl + j) < nrows;
#pragma unroll
            for (int ni = 0; ni < 4; ++ni) {
                int ocol = wc * 64 + ni * 16 + rl;
                float o = acc[mi][ni][j] + bn[ni];
                if (STATS && inb) { ssum[ni] += o; ssq[ni] += o * o; }
                if (POST) o = fmaxf(o, 0.f);
                sA[(rowl + j) * LDA + ocol] = f2b(o);
            }
        }
    }

    if (STATS) {
#pragma unroll
        for (int ni = 0; ni < 4; ++ni) {
            float s = ssum[ni], q = ssq[ni];
            s += __shfl_xor(s, 16, 64); q += __shfl_xor(q, 16, 64);
            s += __shfl_xor(s, 32, 64); q += __shfl_xor(q, 32, 64);
            if (g == 0) {
                int col = wc * 64 + ni * 16 + rl;
                atomicAdd(&lsum[col], s);
                atomicAdd(&lsq[col], q);
            }
        }
    }
    __syncthreads();

    // coalesced output copy (+ global stats flush)
    for (int idx = t; idx < 128 * 16; idx += 256) {
        int r = idx >> 4, c8 = (idx & 15) << 3;
        int rr = r0 + r;
        if (rr < nrows) {
            u32x4 v = *(const u32x4*)&sA[r * LDA + c8];
            __builtin_nontemporal_store(v, (u32x4*)(outp + (size_t)rr * 128 + c8));
        }
    }
    if (STATS && t < 128) {
        atomicAdd(&gsum[t], lsum[t]);
        atomicAdd(&gsq[t], lsq[t]);
    }
}

// ================= fused head: out = sigmoid(relu(h@l1W.T+l1b) @ l2W.T + l2b) ========
__global__ __launch_bounds__(256, 3) void k_head(const ushort* __restrict__ hbf,
                                                 const ushort* __restrict__ l1bf,
                                                 const float* __restrict__ b1f,
                                                 const float* __restrict__ W2,
                                                 const float* __restrict__ b2f_,
                                                 float* __restrict__ out) {
    __shared__ ushort sA[128 * LDA];          // h tile, later reused as z^T tile
    __shared__ float sbias[128];
    __shared__ float w2s[NCLASS * 128];
    __shared__ float b2s[NCLASS];

    int t = threadIdx.x;
    int r0 = blockIdx.x * 128;

    if (t < 128) sbias[t] = b1f[t];
    for (int idx = t; idx < (NCLASS * 128) / 4; idx += 256)
        *(float4*)&w2s[idx * 4] = *(const float4*)(W2 + idx * 4);
    if (t < NCLASS) b2s[t] = b2f_[t];

    for (int idx = t; idx < 128 * 16; idx += 256) {
        int r = idx >> 4, c8 = (idx & 15) << 3;
        int rr = r0 + r;
        u32x4 v = (u32x4){0u, 0u, 0u, 0u};
        if (rr < N_NODES) v = __builtin_nontemporal_load((const u32x4*)(hbf + (size_t)rr * 128 + c8));
        *(u32x4*)&sA[r * LDA + c8] = v;
    }
    __syncthreads();

    int lane = t & 63, wid = t >> 6;
    int rl = lane & 15, g = lane >> 4;
    int wr = wid >> 1, wc = wid & 1;

    f32x4 acc[4][4];
#pragma unroll
    for (int i = 0; i < 4; ++i)
#pragma unroll
        for (int j = 0; j < 4; ++j) acc[i][j] = (f32x4){0.f, 0.f, 0.f, 0.f};

#pragma unroll
    for (int ks = 0; ks < 4; ++ks) {
        int koff = ks * 32 + g * 8;
        bf16x8 a[4], b[4];
#pragma unroll
        for (int ni = 0; ni < 4; ++ni)
            b[ni] = *(const bf16x8*)&l1bf[(size_t)(wc * 64 + ni * 16 + rl) * 128 + koff];
#pragma unroll
        for (int mi = 0; mi < 4; ++mi)
            a[mi] = *(const bf16x8*)&sA[(wr * 64 + mi * 16 + rl) * LDA + koff];
#pragma unroll
        for (int mi = 0; mi < 4; ++mi)
#pragma unroll
            for (int ni = 0; ni < 4; ++ni)
                acc[mi][ni] = __builtin_amdgcn_mfma_f32_16x16x32_bf16(a[mi], b[ni], acc[mi][ni], 0, 0, 0);
    }

    __syncthreads();   // all waves done reading sA -> safe to overwrite with z^T

    float bn[4];
#pragma unroll
    for (int ni = 0; ni < 4; ++ni) bn[ni] = sbias[wc * 64 + ni * 16 + rl];
#pragma unroll
    for (int mi = 0; mi < 4; ++mi) {
        int rowl = wr * 64 + mi * 16 + g * 4;
#pragma unroll
        for (int j = 0; j < 4; ++j) {
#pragma unroll
            for (int ni = 0; ni < 4; ++ni) {
                int ocol = wc * 64 + ni * 16 + rl;
                float o = fmaxf(acc[mi][ni][j] + bn[ni], 0.f);
                sA[ocol * LDA + rowl + j] = f2b(o);   // z^T: [col][row]
            }
        }
    }
    __syncthreads();

    int row = t & 127, ch = t >> 7;
    float acc2[5] = {0.f, 0.f, 0.f, 0.f, 0.f};
    const float* w2p = &w2s[ch * 5 * 128];
#pragma unroll 4
    for (int k = 0; k < 128; ++k) {
        float v = b2f(sA[k * LDA + row]);
#pragma unroll
        for (int c = 0; c < 5; ++c)
            acc2[c] = fmaf(v, w2p[c * 128 + k], acc2[c]);
    }
    int rr = r0 + row;
    if (rr < N_NODES) {
#pragma unroll
        for (int c = 0; c < 5; ++c) {
            float z = acc2[c] + b2s[ch * 5 + c];
            out[(size_t)rr * NCLASS + ch * 5 + c] = 1.f / (1.f + expf(-z));
        }
    }
}

// ================= launcher =================
extern "C" void kernel_launch(void* const* d_in, const int* in_sizes, int n_in,
                              void* d_out, int out_size, void* d_ws, size_t ws_size,
                              hipStream_t stream) {
    const float* x     = (const float*)d_in[0];
    const int*   ei    = (const int*)d_in[1];
    const float* W1    = (const float*)d_in[2];
    const float* b1    = (const float*)d_in[3];
    const float* gamma = (const float*)d_in[4];
    const float* beta  = (const float*)d_in[5];
    const float* W2    = (const float*)d_in[6];
    const float* b2    = (const float*)d_in[7];
    const float* l1W   = (const float*)d_in[8];
    const float* l1b   = (const float*)d_in[9];
    const float* l2W   = (const float*)d_in[10];
    const float* l2b   = (const float*)d_in[11];
    float* out = (float*)d_out;

    char* w = (char*)d_ws;
    ushort* hbf    = (ushort*)(w);                   // 25,600,000 B
    ushort* zbf    = (ushort*)(w + 25600000);        // 25,600,000 B
    ushort* aggout = (ushort*)(w + 51200000);        // 25,600,000 B
    int*   row_ptr = (int*)   (w + 76800000);        // 400,004 B (reserve 400,640)
    int*   csr     = (int*)   (w + 77200640);        // 6,400,000 B
    uint*  tmp     = (uint*)  (w + 83600640);        // 6,400,000 B
    int*   hist    = (int*)   (w + 90000640);        // 800,768 (reserve 801,280)
    int*   psums   = (int*)   (w + 90801920);        // reserve 4,096
    float* gstats  = (float*) (w + 90806016);        // 3 layers x 256 floats = 3072 B
    ushort* wbf    = (ushort*)(w + 90809344);        // 229,376 B
    ushort* w1bf   = wbf;                            // [3][128][128]
    ushort* w2bf   = wbf + 49152;                    // [3][128][128]
    ushort* l1bf   = wbf + 98304;                    // [128][128]

    const int* src = ei;
    const int* dst = ei + N_EDGES;

    // zero all 3 layers' stats buffers once per call
    (void)hipMemsetAsync(gstats, 0, 3072, stream);

    // ---- CSR build (radix partition, zero global atomics) ----
    k_hist<<<NBLK, 256, 0, stream>>>(dst, hist);
    k_scan1<<<SCAN_BLKS, 256, 0, stream>>>(hist, psums);
    k_scan2<<<1, 1024, 0, stream>>>(psums);
    k_partition<<<NBLK, 256, 0, stream>>>(src, dst, hist, psums, tmp);
    k_bucket_fill<<<NBUK, 256, 0, stream>>>(tmp, psums, row_ptr, csr);

    // ---- x + weights -> bf16 ----
    const int CONV_NB = (N_NODES * D / 4 + 28672 + 255) / 256;
    k_conv<<<CONV_NB, 256, 0, stream>>>(x, W1, W2, l1W, hbf, wbf);

    // ---- 3 GIN layers ----
    for (int l = 0; l < NLAYERS; ++l) {
        float* gsum = gstats + l * 256;
        float* gsq  = gsum + 128;
        k_aggregate<<<N_NODES / 4, 256, 0, stream>>>(hbf, row_ptr, csr, aggout);
        // z = (h+agg) @ W1.T + b1  (bf16 out) + fused column stats
        k_gemm<0, 0, 1><<<NBUK, 256, 0, stream>>>(aggout, w1bf + l * D * D, b1 + l * D,
                                                  nullptr, nullptr, zbf, gsum, gsq, N_NODES);
        // h' = relu( relu(BN(z)) @ W2.T + b2 )  (BN finalize inlined in prologue)
        k_gemm<2, 1, 0><<<NBUK, 256, 0, stream>>>(zbf, w2bf + l * D * D, b2 + l * D,
                                                  gamma + l * D, beta + l * D, hbf,
                                                  gsum, gsq, N_NODES);
    }

    // ---- fused head ----
    k_head<<<NBUK, 256, 0, stream>>>(hbf, l1bf, l1b, l2W, l2b, out);
}

// Round 12
// 456.205 us; speedup vs baseline: 1.2826x; 1.0454x over previous
//
#include <hip/hip_runtime.h>
#include <math.h>

#define N_NODES 100000
#define N_EDGES 1600000
#define D 128
#define NCLASS 10
#define NLAYERS 3
#define BN_EPS 1e-5f

#define LDA 136        // padded LDS row stride in bf16 elems
#define BUCKET_SH 7    // 128 nodes per bucket
#define NBUK 782       // ceil(100000/128)
#define NBLK 256       // partition blocks (== scan chunk size -> psums[i] = bucket i base)
#define CHUNK 6250     // N_EDGES / NBLK (exact)
#define SCAN_BLKS NBUK

typedef __attribute__((ext_vector_type(8))) short bf16x8;
typedef __attribute__((ext_vector_type(4))) float f32x4;
typedef __attribute__((ext_vector_type(4))) uint u32x4;

__device__ __forceinline__ ushort f2b(float x) {          // RNE fp32 -> bf16
    uint u = __float_as_uint(x);
    return (ushort)((u + 0x7fffu + ((u >> 16) & 1u)) >> 16);
}
__device__ __forceinline__ float b2f(uint u) {            // bf16 bits -> fp32 (exact)
    return __uint_as_float(u << 16);
}
__device__ __forceinline__ uint pack2(float a, float b) {
    return (uint)f2b(a) | ((uint)f2b(b) << 16);
}

// ================= CSR build: radix partition, no global atomics =================
// (also zeroes the per-layer BN-stats accumulators -> saves a memset dispatch)
__global__ __launch_bounds__(256) void k_hist(const int* __restrict__ dst,
                                              int* __restrict__ hist,
                                              float* __restrict__ gstats) {
    __shared__ int lh[NBUK];
    int t = threadIdx.x, b = blockIdx.x;
    if (b == 0) {
        for (int i = t; i < NLAYERS * 256; i += 256) gstats[i] = 0.f;
    }
    for (int i = t; i < NBUK; i += 256) lh[i] = 0;
    __syncthreads();
    int e0 = b * CHUNK;
    for (int e = e0 + t; e < e0 + CHUNK; e += 256)
        atomicAdd(&lh[dst[e] >> BUCKET_SH], 1);
    __syncthreads();
    for (int i = t; i < NBUK; i += 256) hist[i * NBLK + b] = lh[i];
}

__global__ __launch_bounds__(256) void k_scan1(int* __restrict__ hist, int* __restrict__ psums) {
    __shared__ int sh[256];
    int t = threadIdx.x;
    int i = blockIdx.x * 256 + t;
    int v = hist[i];
    sh[t] = v; __syncthreads();
    for (int off = 1; off < 256; off <<= 1) {
        int a = (t >= off) ? sh[t - off] : 0;
        __syncthreads();
        sh[t] += a;
        __syncthreads();
    }
    hist[i] = sh[t] - v;
    if (t == 255) psums[blockIdx.x] = sh[255];
}

__global__ __launch_bounds__(1024) void k_scan2(int* __restrict__ psums) {
    __shared__ int sh[1024];
    int t = threadIdx.x;
    int v = (t < SCAN_BLKS) ? psums[t] : 0;
    sh[t] = v; __syncthreads();
    for (int off = 1; off < 1024; off <<= 1) {
        int a = (t >= off) ? sh[t - off] : 0;
        __syncthreads();
        sh[t] += a;
        __syncthreads();
    }
    if (t < SCAN_BLKS) psums[t] = sh[t] - v;
}

__global__ __launch_bounds__(256) void k_partition(const int* __restrict__ src,
                                                   const int* __restrict__ dst,
                                                   const int* __restrict__ hist,
                                                   const int* __restrict__ psums,
                                                   uint* __restrict__ tmp) {
    __shared__ int lcur[NBUK];
    int t = threadIdx.x, b = blockIdx.x;
    for (int i = t; i < NBUK; i += 256) lcur[i] = hist[i * NBLK + b] + psums[i];
    __syncthreads();
    int e0 = b * CHUNK;
    for (int e = e0 + t; e < e0 + CHUNK; e += 256) {
        int d = dst[e];
        int bk = d >> BUCKET_SH;
        int pos = atomicAdd(&lcur[bk], 1);
        tmp[pos] = (uint)src[e] | ((uint)(d & ((1 << BUCKET_SH) - 1)) << 17);
    }
}

__global__ __launch_bounds__(256) void k_bucket_fill(const uint* __restrict__ tmp,
                                                     const int* __restrict__ psums,
                                                     int* __restrict__ row_ptr,
                                                     int* __restrict__ csr) {
    __shared__ int hist[128], inc[128], cur[128];
    int b = blockIdx.x, t = threadIdx.x;
    int base = psums[b];
    int end  = (b + 1 < NBUK) ? psums[b + 1] : N_EDGES;
    int nb = end - base;
    int lo = b << BUCKET_SH;
    const uint* bt = tmp + base;

    if (t < 128) hist[t] = 0;
    __syncthreads();
    for (int i = t; i < nb; i += 256)
        atomicAdd(&hist[bt[i] >> 17], 1);
    __syncthreads();
    if (t < 128) inc[t] = hist[t];
    __syncthreads();
    for (int offs = 1; offs < 128; offs <<= 1) {
        int a = (t < 128 && t >= offs) ? inc[t - offs] : 0;
        __syncthreads();
        if (t < 128) inc[t] += a;
        __syncthreads();
    }
    if (t < 128) {
        int node = lo + t;
        if (node < N_NODES) row_ptr[node] = base + inc[t] - hist[t];
        cur[t] = 0;
    }
    if (b == NBUK - 1 && t == 0) row_ptr[N_NODES] = base + nb;
    __syncthreads();
    for (int i = t; i < nb; i += 256) {
        uint u = bt[i];
        int dl = u >> 17;
        int s = (int)(u & 0x1ffffu);
        int p = atomicAdd(&cur[dl], 1);
        csr[base + (inc[dl] - hist[dl]) + p] = s;
    }
}

// ================= fp32 -> bf16: x and all weights =================
__global__ void k_conv(const float* __restrict__ x, const float* __restrict__ W1,
                       const float* __restrict__ W2, const float* __restrict__ l1W,
                       ushort* __restrict__ hbf, ushort* __restrict__ wbf) {
    int i = blockIdx.x * 256 + threadIdx.x;
    const int n4x = N_NODES * D / 4;               // 3,200,000
    if (i < n4x) {
        float4 v = ((const float4*)x)[i];
        uint2 u;
        u.x = pack2(v.x, v.y);
        u.y = pack2(v.z, v.w);
        ((uint2*)hbf)[i] = u;
    } else {
        int k = i - n4x;                           // float4 index into weights
        const float* srcp;
        ushort* dstp;
        if (k < 12288)      { srcp = W1 + k * 4;            dstp = wbf + k * 4; }
        else if (k < 24576) { srcp = W2 + (k - 12288) * 4;  dstp = wbf + 49152 + (k - 12288) * 4; }
        else if (k < 28672) { srcp = l1W + (k - 24576) * 4; dstp = wbf + 98304 + (k - 24576) * 4; }
        else return;
        float4 v = *(const float4*)srcp;
        ushort4 u;
        u.x = f2b(v.x); u.y = f2b(v.y); u.z = f2b(v.z); u.w = f2b(v.w);
        *(ushort4*)dstp = u;
    }
}

// ================= aggregation (4B lanes, 1 row/instr, 8-deep) =================
__global__ __launch_bounds__(256) void k_aggregate(const ushort* __restrict__ hbf,
                                                   const int* __restrict__ row_ptr,
                                                   const int* __restrict__ csr,
                                                   ushort* __restrict__ outbf) {
    int node = blockIdx.x * 4 + (threadIdx.x >> 6);
    int lane = threadIdx.x & 63;
    const uint* hp = (const uint*)hbf;
    uint self = hp[(size_t)node * 64 + lane];
    float ax = b2f(self & 0xffffu), ay = b2f(self >> 16);
    int e0 = row_ptr[node], e1 = row_ptr[node + 1];
    int e = e0;
    for (; e + 7 < e1; e += 8) {
        uint v0 = hp[(size_t)csr[e]     * 64 + lane];
        uint v1 = hp[(size_t)csr[e + 1] * 64 + lane];
        uint v2 = hp[(size_t)csr[e + 2] * 64 + lane];
        uint v3 = hp[(size_t)csr[e + 3] * 64 + lane];
        uint v4 = hp[(size_t)csr[e + 4] * 64 + lane];
        uint v5 = hp[(size_t)csr[e + 5] * 64 + lane];
        uint v6 = hp[(size_t)csr[e + 6] * 64 + lane];
        uint v7 = hp[(size_t)csr[e + 7] * 64 + lane];
        ax += b2f(v0 & 0xffffu); ay += b2f(v0 >> 16);
        ax += b2f(v1 & 0xffffu); ay += b2f(v1 >> 16);
        ax += b2f(v2 & 0xffffu); ay += b2f(v2 >> 16);
        ax += b2f(v3 & 0xffffu); ay += b2f(v3 >> 16);
        ax += b2f(v4 & 0xffffu); ay += b2f(v4 >> 16);
        ax += b2f(v5 & 0xffffu); ay += b2f(v5 >> 16);
        ax += b2f(v6 & 0xffffu); ay += b2f(v6 >> 16);
        ax += b2f(v7 & 0xffffu); ay += b2f(v7 >> 16);
    }
    for (; e < e1; ++e) {
        uint v = hp[(size_t)csr[e] * 64 + lane];
        ax += b2f(v & 0xffffu); ay += b2f(v >> 16);
    }
    ((uint*)outbf)[(size_t)node * 64 + lane] = pack2(ax, ay);
}

// ================= MFMA GEMM: A from LDS, W(bf16) direct from global =================
// PRE: 0 = copy bf16 A; 2 = BN finalize from gsum/gsq in prologue, apply relu(a*sc+sf).
// POST: 1 = relu.  STATS: fused column sum/sumsq -> gsum/gsq atomics.
// Output bf16 via LDS-bounce coalesced stores (kept in cache for the consumer).
template <int PRE, int POST, int STATS>
__global__ __launch_bounds__(256, 4) void k_gemm(const ushort* __restrict__ inA,
                                                 const ushort* __restrict__ Wbf,
                                                 const float* __restrict__ bias,
                                                 const float* __restrict__ gamma,
                                                 const float* __restrict__ beta,
                                                 ushort* __restrict__ outp,
                                                 float* __restrict__ gsum,
                                                 float* __restrict__ gsq,
                                                 int nrows) {
    __shared__ ushort sA[128 * LDA];
    __shared__ float sbias[128];
    __shared__ float lsum[128], lsq[128];
    __shared__ float sscale[128], sshift[128];

    int t = threadIdx.x;
    int r0 = blockIdx.x * 128;

    if (t < 128) {
        sbias[t] = bias[t];
        if (STATS) { lsum[t] = 0.f; lsq[t] = 0.f; }
        if (PRE == 2) {
            float s = gsum[t], q = gsq[t];
            float mu = s * (1.f / N_NODES);
            float var = q * (1.f / N_NODES) - mu * mu;
            float rstd = rsqrtf(var + BN_EPS);
            float sc = rstd * gamma[t];
            sscale[t] = sc;
            sshift[t] = beta[t] - mu * sc;
        }
    }
    if (PRE == 2) __syncthreads();   // stage loop consumes sscale/sshift

    for (int idx = t; idx < 128 * 16; idx += 256) {
        int r = idx >> 4, c8 = (idx & 15) << 3;
        int rr = r0 + r;
        u32x4 v = (u32x4){0u, 0u, 0u, 0u};
        if (rr < nrows) v = __builtin_nontemporal_load((const u32x4*)(inA + (size_t)rr * 128 + c8));
        if (PRE == 2) {
            float f0 = b2f(v.x & 0xffffu), f1 = b2f(v.x >> 16);
            float f2 = b2f(v.y & 0xffffu), f3 = b2f(v.y >> 16);
            float f4 = b2f(v.z & 0xffffu), f5 = b2f(v.z >> 16);
            float f6 = b2f(v.w & 0xffffu), f7 = b2f(v.w >> 16);
            float4 sc0 = *(const float4*)&sscale[c8];
            float4 sc1 = *(const float4*)&sscale[c8 + 4];
            float4 sf0 = *(const float4*)&sshift[c8];
            float4 sf1 = *(const float4*)&sshift[c8 + 4];
            f0 = fmaxf(fmaf(f0, sc0.x, sf0.x), 0.f);
            f1 = fmaxf(fmaf(f1, sc0.y, sf0.y), 0.f);
            f2 = fmaxf(fmaf(f2, sc0.z, sf0.z), 0.f);
            f3 = fmaxf(fmaf(f3, sc0.w, sf0.w), 0.f);
            f4 = fmaxf(fmaf(f4, sc1.x, sf1.x), 0.f);
            f5 = fmaxf(fmaf(f5, sc1.y, sf1.y), 0.f);
            f6 = fmaxf(fmaf(f6, sc1.z, sf1.z), 0.f);
            f7 = fmaxf(fmaf(f7, sc1.w, sf1.w), 0.f);
            v.x = pack2(f0, f1); v.y = pack2(f2, f3);
            v.z = pack2(f4, f5); v.w = pack2(f6, f7);
        }
        *(u32x4*)&sA[r * LDA + c8] = v;
    }
    __syncthreads();

    int lane = t & 63, wid = t >> 6;
    int rl = lane & 15, g = lane >> 4;
    int wr = wid >> 1, wc = wid & 1;

    f32x4 acc[4][4];
#pragma unroll
    for (int i = 0; i < 4; ++i)
#pragma unroll
        for (int j = 0; j < 4; ++j) acc[i][j] = (f32x4){0.f, 0.f, 0.f, 0.f};

#pragma unroll
    for (int ks = 0; ks < 4; ++ks) {
        int koff = ks * 32 + g * 8;
        bf16x8 a[4], b[4];
#pragma unroll
        for (int ni = 0; ni < 4; ++ni)
            b[ni] = *(const bf16x8*)&Wbf[(size_t)(wc * 64 + ni * 16 + rl) * 128 + koff];
#pragma unroll
        for (int mi = 0; mi < 4; ++mi)
            a[mi] = *(const bf16x8*)&sA[(wr * 64 + mi * 16 + rl) * LDA + koff];
#pragma unroll
        for (int mi = 0; mi < 4; ++mi)
#pragma unroll
            for (int ni = 0; ni < 4; ++ni)
                acc[mi][ni] = __builtin_amdgcn_mfma_f32_16x16x32_bf16(a[mi], b[ni], acc[mi][ni], 0, 0, 0);
    }
    __syncthreads();   // all MFMA reads of sA complete -> sA reusable as out bounce

    float bn[4], ssum[4], ssq[4];
#pragma unroll
    for (int ni = 0; ni < 4; ++ni) {
        bn[ni] = sbias[wc * 64 + ni * 16 + rl];
        ssum[ni] = 0.f; ssq[ni] = 0.f;
    }

#pragma unroll
    for (int mi = 0; mi < 4; ++mi) {
        int rowl = wr * 64 + mi * 16 + g * 4;
#pragma unroll
        for (int j = 0; j < 4; ++j) {
            bool inb = (r0 + rowl + j) < nrows;
#pragma unroll
            for (int ni = 0; ni < 4; ++ni) {
                int ocol = wc * 64 + ni * 16 + rl;
                float o = acc[mi][ni][j] + bn[ni];
                if (STATS && inb) { ssum[ni] += o; ssq[ni] += o * o; }
                if (POST) o = fmaxf(o, 0.f);
                sA[(rowl + j) * LDA + ocol] = f2b(o);
            }
        }
    }

    if (STATS) {
#pragma unroll
        for (int ni = 0; ni < 4; ++ni) {
            float s = ssum[ni], q = ssq[ni];
            s += __shfl_xor(s, 16, 64); q += __shfl_xor(q, 16, 64);
            s += __shfl_xor(s, 32, 64); q += __shfl_xor(q, 32, 64);
            if (g == 0) {
                int col = wc * 64 + ni * 16 + rl;
                atomicAdd(&lsum[col], s);
                atomicAdd(&lsq[col], q);
            }
        }
    }
    __syncthreads();

    // coalesced output copy (plain stores -> stays cached for the consumer kernel)
    for (int idx = t; idx < 128 * 16; idx += 256) {
        int r = idx >> 4, c8 = (idx & 15) << 3;
        int rr = r0 + r;
        if (rr < nrows) {
            u32x4 v = *(const u32x4*)&sA[r * LDA + c8];
            *(u32x4*)(outp + (size_t)rr * 128 + c8) = v;
        }
    }
    if (STATS && t < 128) {
        atomicAdd(&gsum[t], lsum[t]);
        atomicAdd(&gsq[t], lsq[t]);
    }
}

// ================= fused head: out = sigmoid(relu(h@l1W.T+l1b) @ l2W.T + l2b) ========
__global__ __launch_bounds__(256, 3) void k_head(const ushort* __restrict__ hbf,
                                                 const ushort* __restrict__ l1bf,
                                                 const float* __restrict__ b1f,
                                                 const float* __restrict__ W2,
                                                 const float* __restrict__ b2f_,
                                                 float* __restrict__ out) {
    __shared__ ushort sA[128 * LDA];          // h tile, later reused as z^T tile
    __shared__ float sbias[128];
    __shared__ float w2s[NCLASS * 128];
    __shared__ float b2s[NCLASS];

    int t = threadIdx.x;
    int r0 = blockIdx.x * 128;

    if (t < 128) sbias[t] = b1f[t];
    for (int idx = t; idx < (NCLASS * 128) / 4; idx += 256)
        *(float4*)&w2s[idx * 4] = *(const float4*)(W2 + idx * 4);
    if (t < NCLASS) b2s[t] = b2f_[t];

    for (int idx = t; idx < 128 * 16; idx += 256) {
        int r = idx >> 4, c8 = (idx & 15) << 3;
        int rr = r0 + r;
        u32x4 v = (u32x4){0u, 0u, 0u, 0u};
        if (rr < N_NODES) v = __builtin_nontemporal_load((const u32x4*)(hbf + (size_t)rr * 128 + c8));
        *(u32x4*)&sA[r * LDA + c8] = v;
    }
    __syncthreads();

    int lane = t & 63, wid = t >> 6;
    int rl = lane & 15, g = lane >> 4;
    int wr = wid >> 1, wc = wid & 1;

    f32x4 acc[4][4];
#pragma unroll
    for (int i = 0; i < 4; ++i)
#pragma unroll
        for (int j = 0; j < 4; ++j) acc[i][j] = (f32x4){0.f, 0.f, 0.f, 0.f};

#pragma unroll
    for (int ks = 0; ks < 4; ++ks) {
        int koff = ks * 32 + g * 8;
        bf16x8 a[4], b[4];
#pragma unroll
        for (int ni = 0; ni < 4; ++ni)
            b[ni] = *(const bf16x8*)&l1bf[(size_t)(wc * 64 + ni * 16 + rl) * 128 + koff];
#pragma unroll
        for (int mi = 0; mi < 4; ++mi)
            a[mi] = *(const bf16x8*)&sA[(wr * 64 + mi * 16 + rl) * LDA + koff];
#pragma unroll
        for (int mi = 0; mi < 4; ++mi)
#pragma unroll
            for (int ni = 0; ni < 4; ++ni)
                acc[mi][ni] = __builtin_amdgcn_mfma_f32_16x16x32_bf16(a[mi], b[ni], acc[mi][ni], 0, 0, 0);
    }

    __syncthreads();   // all waves done reading sA -> safe to overwrite with z^T

    float bn[4];
#pragma unroll
    for (int ni = 0; ni < 4; ++ni) bn[ni] = sbias[wc * 64 + ni * 16 + rl];
#pragma unroll
    for (int mi = 0; mi < 4; ++mi) {
        int rowl = wr * 64 + mi * 16 + g * 4;
#pragma unroll
        for (int j = 0; j < 4; ++j) {
#pragma unroll
            for (int ni = 0; ni < 4; ++ni) {
                int ocol = wc * 64 + ni * 16 + rl;
                float o = fmaxf(acc[mi][ni][j] + bn[ni], 0.f);
                sA[ocol * LDA + rowl + j] = f2b(o);   // z^T: [col][row]
            }
        }
    }
    __syncthreads();

    int row = t & 127, ch = t >> 7;
    float acc2[5] = {0.f, 0.f, 0.f, 0.f, 0.f};
    const float* w2p = &w2s[ch * 5 * 128];
#pragma unroll 4
    for (int k = 0; k < 128; ++k) {
        float v = b2f(sA[k * LDA + row]);
#pragma unroll
        for (int c = 0; c < 5; ++c)
            acc2[c] = fmaf(v, w2p[c * 128 + k], acc2[c]);
    }
    int rr = r0 + row;
    if (rr < N_NODES) {
#pragma unroll
        for (int c = 0; c < 5; ++c) {
            float z = acc2[c] + b2s[ch * 5 + c];
            out[(size_t)rr * NCLASS + ch * 5 + c] = 1.f / (1.f + expf(-z));
        }
    }
}

// ================= launcher =================
extern "C" void kernel_launch(void* const* d_in, const int* in_sizes, int n_in,
                              void* d_out, int out_size, void* d_ws, size_t ws_size,
                              hipStream_t stream) {
    const float* x     = (const float*)d_in[0];
    const int*   ei    = (const int*)d_in[1];
    const float* W1    = (const float*)d_in[2];
    const float* b1    = (const float*)d_in[3];
    const float* gamma = (const float*)d_in[4];
    const float* beta  = (const float*)d_in[5];
    const float* W2    = (const float*)d_in[6];
    const float* b2    = (const float*)d_in[7];
    const float* l1W   = (const float*)d_in[8];
    const float* l1b   = (const float*)d_in[9];
    const float* l2W   = (const float*)d_in[10];
    const float* l2b   = (const float*)d_in[11];
    float* out = (float*)d_out;

    char* w = (char*)d_ws;
    ushort* hbf    = (ushort*)(w);                   // 25,600,000 B
    ushort* zbf    = (ushort*)(w + 25600000);        // 25,600,000 B
    ushort* aggout = (ushort*)(w + 51200000);        // 25,600,000 B
    int*   row_ptr = (int*)   (w + 76800000);        // 400,004 B (reserve 400,640)
    int*   csr     = (int*)   (w + 77200640);        // 6,400,000 B
    uint*  tmp     = (uint*)  (w + 83600640);        // 6,400,000 B
    int*   hist    = (int*)   (w + 90000640);        // 800,768 (reserve 801,280)
    int*   psums   = (int*)   (w + 90801920);        // reserve 4,096
    float* gstats  = (float*) (w + 90806016);        // 3 layers x 256 floats = 3072 B
    ushort* wbf    = (ushort*)(w + 90809344);        // 229,376 B
    ushort* w1bf   = wbf;                            // [3][128][128]
    ushort* w2bf   = wbf + 49152;                    // [3][128][128]
    ushort* l1bf   = wbf + 98304;                    // [128][128]

    const int* src = ei;
    const int* dst = ei + N_EDGES;

    // ---- CSR build (radix partition, zero global atomics; also zeroes gstats) ----
    k_hist<<<NBLK, 256, 0, stream>>>(dst, hist, gstats);
    k_scan1<<<SCAN_BLKS, 256, 0, stream>>>(hist, psums);
    k_scan2<<<1, 1024, 0, stream>>>(psums);
    k_partition<<<NBLK, 256, 0, stream>>>(src, dst, hist, psums, tmp);
    k_bucket_fill<<<NBUK, 256, 0, stream>>>(tmp, psums, row_ptr, csr);

    // ---- x + weights -> bf16 ----
    const int CONV_NB = (N_NODES * D / 4 + 28672 + 255) / 256;
    k_conv<<<CONV_NB, 256, 0, stream>>>(x, W1, W2, l1W, hbf, wbf);

    // ---- 3 GIN layers ----
    for (int l = 0; l < NLAYERS; ++l) {
        float* gsum = gstats + l * 256;
        float* gsq  = gsum + 128;
        k_aggregate<<<N_NODES / 4, 256, 0, stream>>>(hbf, row_ptr, csr, aggout);
        // z = (h+agg) @ W1.T + b1  (bf16 out) + fused column stats
        k_gemm<0, 0, 1><<<NBUK, 256, 0, stream>>>(aggout, w1bf + l * D * D, b1 + l * D,
                                                  nullptr, nullptr, zbf, gsum, gsq, N_NODES);
        // h' = relu( relu(BN(z)) @ W2.T + b2 )  (BN finalize inlined in prologue)
        k_gemm<2, 1, 0><<<NBUK, 256, 0, stream>>>(zbf, w2bf + l * D * D, b2 + l * D,
                                                  gamma + l * D, beta + l * D, hbf,
                                                  gsum, gsq, N_NODES);
    }

    // ---- fused head ----
    k_head<<<NBUK, 256, 0, stream>>>(hbf, l1bf, l1b, l2W, l2b, out);
}